// Round 11
// baseline (195.537 us; speedup 1.0000x reference)
//
#include <hip/hip_runtime.h>

// Problem constants (from reference setup_inputs)
constexpr int Bc = 8;
constexpr int Nc = 300;
constexpr int Cc = 256;
constexpr int Pc = 32;

typedef float f32x4 __attribute__((ext_vector_type(4)));

// Staged levels 1..3 only: 2500 + 625 + 169 = 3294 floats used;
// padded to 3296 (13,184 B, multiple of 16) so both slice buffers stay
// 16B-aligned for the width-16 global_load_lds destination.
constexpr int L1_OFF = 0;
constexpr int L2_OFF = 2500;
constexpr int L3_OFF = 3125;
constexpr int STAGE_FLOATS = 3296;   // padded per-slice buffer

// ---- async global->LDS DMA ----
__device__ __forceinline__ void gl_lds16(const void* g, void* l) {
    __builtin_amdgcn_global_load_lds(
        (const __attribute__((address_space(1))) void*)g,
        (__attribute__((address_space(3))) void*)l, 16, 0, 0);
}
__device__ __forceinline__ void gl_lds4(const void* g, void* l) {
    __builtin_amdgcn_global_load_lds(
        (const __attribute__((address_space(1))) void*)g,
        (__attribute__((address_space(3))) void*)l, 4, 0, 0);
}

// ---------------------------------------------------------------------------
// Kernel 1: per-query params, one wave per query.
// params[q*8 + {0:sx, 1:sy, 2..5: zw[l], 6..7: unused}]
// ---------------------------------------------------------------------------
__global__ __launch_bounds__(256) void params_kernel(
    const float* __restrict__ qpos, const float* __restrict__ qcont,
    const float* __restrict__ Woff, const float* __restrict__ boff,
    const float* __restrict__ sigma, float* __restrict__ params)
{
    const int w = threadIdx.x >> 6;
    const int lane = threadIdx.x & 63;
    const int q = blockIdx.x * 4 + w;          // 600*4 = 2400 queries

    f32x4 qc = *(const f32x4*)&qcont[(size_t)q * Cc + lane * 4];
    float p0 = 0.f, p1 = 0.f, p2 = 0.f;
#pragma unroll
    for (int j = 0; j < 4; ++j) {
        const float* wr = &Woff[(lane * 4 + j) * 3];
        p0 += qc[j] * wr[0];
        p1 += qc[j] * wr[1];
        p2 += qc[j] * wr[2];
    }
#pragma unroll
    for (int off = 32; off > 0; off >>= 1) {
        p0 += __shfl_down(p0, off, 64);
        p1 += __shfl_down(p1, off, 64);
        p2 += __shfl_down(p2, off, 64);
    }
    if (lane == 0) {
        float dx = p0 + boff[0];
        float dy = p1 + boff[1];
        float dz = p2 + boff[2];
        float x = qpos[q * 4 + 0];
        float y = qpos[q * 4 + 1];
        float z = qpos[q * 4 + 2];
        float r = qpos[q * 4 + 3];
        float sx = x + dx * exp2f(z - r);
        float sy = y + dy * exp2f(z + r);
        float sz = z + dz;
        float sg = sigma[0];
        float inv = 1.0f / (2.0f * sg * sg);
        float e[4];
        float s = 0.f;
#pragma unroll
        for (int l = 0; l < 4; ++l) {
            float d = sz - (float)l;
            float wgt = __expf(-d * d * inv);  // gaussian weight in (0,1]
            e[l] = __expf(wgt);                // softmax numerator of that weight
            s += e[l];
        }
        float rs = 1.0f / s;
        params[q * 8 + 0] = sx;
        params[q * 8 + 1] = sy;
#pragma unroll
        for (int l = 0; l < 4; ++l) params[q * 8 + 2 + l] = e[l] * rs;
    }
}

// bilinear coords, border padding, align_corners=False
struct BilinW { int i00, i01, i10, i11; float wx, wy; };
__device__ __forceinline__ BilinW bilin(int W, float sx, float sy) {
    float px = fminf(fmaxf(sx - 0.5f, 0.f), (float)(W - 1));
    float py = fminf(fmaxf(sy - 0.5f, 0.f), (float)(W - 1));
    float x0f = floorf(px);
    float y0f = floorf(py);
    int x0 = (int)x0f;
    int y0 = (int)y0f;
    int x1 = min(x0 + 1, W - 1);
    int y1 = min(y0 + 1, W - 1);
    BilinW r;
    r.wx = px - x0f;
    r.wy = py - y0f;
    r.i00 = y0 * W + x0; r.i01 = y0 * W + x1;
    r.i10 = y1 * W + x0; r.i11 = y1 * W + x1;
    return r;
}
__device__ __forceinline__ float blend(float v00, float v01, float v10, float v11,
                                       float wx, float wy) {
    float top = v00 + wx * (v01 - v00);
    float bot = v10 + wx * (v11 - v10);
    return top + wy * (bot - top);
}

// issue async DMA of levels 1..3 of slice bc into LDS buffer buf
__device__ __forceinline__ void issue_stage_dma(
    const float* __restrict__ f1, const float* __restrict__ f2,
    const float* __restrict__ f3, int bc, float* __restrict__ buf,
    int wave, int lane)
{
    // level 1: 10000 B, 16B-aligned. 9 x 1024 B + 784 B tail (49 lanes).
    const char* g1 = (const char*)(f1 + (size_t)bc * 2500);
    char* l1 = (char*)&buf[L1_OFF];
    for (int i = wave; i < 9; i += 4)
        gl_lds16(g1 + i * 1024 + lane * 16, l1 + i * 1024);
    if (wave == 2 && lane < 49)
        gl_lds16(g1 + 9 * 1024 + lane * 16, l1 + 9 * 1024);
    // level 2: 2500 B, 4B-aligned -> width-4. 9 x 256 B + 196 B tail.
    const char* g2 = (const char*)(f2 + (size_t)bc * 625);
    char* l2 = (char*)&buf[L2_OFF];
    for (int i = wave; i < 9; i += 4)
        gl_lds4(g2 + i * 256 + lane * 4, l2 + i * 256);
    if (wave == 1 && lane < 49)
        gl_lds4(g2 + 9 * 256 + lane * 4, l2 + 9 * 256);
    // level 3: 676 B, 4B-aligned -> width-4. 2 x 256 B + 164 B tail.
    const char* g3 = (const char*)(f3 + (size_t)bc * 169);
    char* l3 = (char*)&buf[L3_OFF];
    for (int i = wave; i < 2; i += 4)
        gl_lds4(g3 + i * 256 + lane * 4, l3 + i * 256);
    if (wave == 3 && lane < 41)
        gl_lds4(g3 + 2 * 256 + lane * 4, l3 + 2 * 256);
}

// ---------------------------------------------------------------------------
// Kernel 2: one block per TWO (b,c) slices, grid 1024 (6 blocks/CU via
// __launch_bounds__(256,6); ~26 KB LDS). Both slices' levels 1..3 DMA'd
// up-front (2x outstanding bytes); level 0 gathered directly from global.
// Level weights: pa.z,pa.w = zw[0],zw[1]; pb.x,pb.y = zw[2],zw[3].
// outT[(b*Cc + c)*Nc + n]  <- coalesced (thread index = n)
// ---------------------------------------------------------------------------
__global__ __launch_bounds__(256, 6) void sample_kernel(
    const float* __restrict__ f0, const float* __restrict__ f1,
    const float* __restrict__ f2, const float* __restrict__ f3,
    const float* __restrict__ params, float* __restrict__ outT)
{
    __shared__ __align__(16) float sl[2][STAGE_FLOATS];
    const int bc0 = blockIdx.x * 2;      // first of two slices (same b: 2|256)
    const int t = threadIdx.x;
    const int b = bc0 >> 8;
    const int wave = t >> 6;
    const int lane = t & 63;

    // ---- per-thread query params (shared by both slices) ----
    const int q0 = b * Nc + t;
    const bool has2 = (t < Nc - 256);    // t < 44
    f32x4 pa0 = *(const f32x4*)&params[(size_t)q0 * 8];      // {sx, sy, zw0, zw1}
    f32x4 pb0 = *(const f32x4*)&params[(size_t)q0 * 8 + 4];  // {zw2, zw3, -, -}
    f32x4 pa1 = {0, 0, 0, 0}, pb1 = {0, 0, 0, 0};
    if (has2) {
        pa1 = *(const f32x4*)&params[(size_t)(q0 + 256) * 8];
        pb1 = *(const f32x4*)&params[(size_t)(q0 + 256) * 8 + 4];
    }
    const float sx0 = pa0.x, sy0 = pa0.y;
    const float sx1 = pa1.x, sy1 = pa1.y;

    // ---- async-stage levels 1..3 of both slices ----
    issue_stage_dma(f1, f2, f3, bc0,     sl[0], wave, lane);
    issue_stage_dma(f1, f2, f3, bc0 + 1, sl[1], wave, lane);

    // ---- level-0 direct gathers for both slices (overlap DMA latency) ----
    const BilinW w0q0 = bilin(100, sx0, sy0);
    BilinW w0q1;
    if (has2) w0q1 = bilin(100, sx1, sy1);

    float g[2][2][4];   // [slice][query][corner]
#pragma unroll
    for (int s = 0; s < 2; ++s) {
        const float* base0 = f0 + (size_t)(bc0 + s) * 10000;
        g[s][0][0] = base0[w0q0.i00];
        g[s][0][1] = base0[w0q0.i01];
        g[s][0][2] = base0[w0q0.i10];
        g[s][0][3] = base0[w0q0.i11];
        if (has2) {
            g[s][1][0] = base0[w0q1.i00];
            g[s][1][1] = base0[w0q1.i01];
            g[s][1][2] = base0[w0q1.i10];
            g[s][1][3] = base0[w0q1.i11];
        }
    }

    __syncthreads();   // drains all DMA + gathers

    // ---- bilinear index sets for staged levels (shared across slices) ----
    const BilinW w1q0 = bilin(50, sx0, sy0);
    const BilinW w2q0 = bilin(25, sx0, sy0);
    const BilinW w3q0 = bilin(13, sx0, sy0);
    BilinW w1q1, w2q1, w3q1;
    if (has2) {
        w1q1 = bilin(50, sx1, sy1);
        w2q1 = bilin(25, sx1, sy1);
        w3q1 = bilin(13, sx1, sy1);
    }

#pragma unroll
    for (int s = 0; s < 2; ++s) {
        const float* buf = sl[s];
        const size_t obase = (size_t)(bc0 + s) * Nc;
        {
            float acc = pa0.z * blend(g[s][0][0], g[s][0][1], g[s][0][2], g[s][0][3],
                                      w0q0.wx, w0q0.wy)
                      + pa0.w * blend(buf[L1_OFF + w1q0.i00], buf[L1_OFF + w1q0.i01],
                                      buf[L1_OFF + w1q0.i10], buf[L1_OFF + w1q0.i11],
                                      w1q0.wx, w1q0.wy)
                      + pb0.x * blend(buf[L2_OFF + w2q0.i00], buf[L2_OFF + w2q0.i01],
                                      buf[L2_OFF + w2q0.i10], buf[L2_OFF + w2q0.i11],
                                      w2q0.wx, w2q0.wy)
                      + pb0.y * blend(buf[L3_OFF + w3q0.i00], buf[L3_OFF + w3q0.i01],
                                      buf[L3_OFF + w3q0.i10], buf[L3_OFF + w3q0.i11],
                                      w3q0.wx, w3q0.wy);
            outT[obase + t] = acc;
        }
        if (has2) {
            float acc = pa1.z * blend(g[s][1][0], g[s][1][1], g[s][1][2], g[s][1][3],
                                      w0q1.wx, w0q1.wy)
                      + pa1.w * blend(buf[L1_OFF + w1q1.i00], buf[L1_OFF + w1q1.i01],
                                      buf[L1_OFF + w1q1.i10], buf[L1_OFF + w1q1.i11],
                                      w1q1.wx, w1q1.wy)
                      + pb1.x * blend(buf[L2_OFF + w2q1.i00], buf[L2_OFF + w2q1.i01],
                                      buf[L2_OFF + w2q1.i10], buf[L2_OFF + w2q1.i11],
                                      w2q1.wx, w2q1.wy)
                      + pb1.y * blend(buf[L3_OFF + w3q1.i00], buf[L3_OFF + w3q1.i01],
                                      buf[L3_OFF + w3q1.i10], buf[L3_OFF + w3q1.i11],
                                      w3q1.wx, w3q1.wy);
            outT[obase + t + 256] = acc;
        }
    }
}

// ---------------------------------------------------------------------------
// Kernel 3: one block per query. Read 256 channel values (strided dwords,
// L2-absorbed: outT footprint 2.46 MB), broadcast over P with NT float4.
// ---------------------------------------------------------------------------
__global__ __launch_bounds__(256) void broadcast_kernel(
    const float* __restrict__ outT, float* __restrict__ out)
{
    __shared__ float sval[Cc];
    const int q = blockIdx.x;            // b*Nc + n
    const int b = q / Nc;
    const int n = q - b * Nc;
    const int c = threadIdx.x;
    sval[c] = outT[((size_t)(b * Cc + c)) * Nc + n];
    __syncthreads();

    const int wave = threadIdx.x >> 6;
    const int c4 = (threadIdx.x & 63) * 4;
    f32x4 val = *(const f32x4*)&sval[c4];
    float* obase = out + (size_t)q * (Pc * Cc) + c4;
#pragma unroll
    for (int p = wave; p < Pc; p += 4) {
        __builtin_nontemporal_store(val, (f32x4*)(obase + p * Cc));
    }
}

// ---------------------------------------------------------------------------
// Fallback: proven single-kernel path (if ws too small). Not expected to run.
// ---------------------------------------------------------------------------
__global__ __launch_bounds__(256) void sampling3d_fallback(
    const float* __restrict__ f0, const float* __restrict__ f1,
    const float* __restrict__ f2, const float* __restrict__ f3,
    const float* __restrict__ qpos, const float* __restrict__ qcont,
    const float* __restrict__ Woff, const float* __restrict__ boff,
    const float* __restrict__ sigma, float* __restrict__ out)
{
    const int q = blockIdx.x;
    const int b = q / Nc;
    const int c = threadIdx.x;
    float qc = qcont[q * Cc + c];
    float p0 = qc * Woff[c * 3 + 0];
    float p1 = qc * Woff[c * 3 + 1];
    float p2 = qc * Woff[c * 3 + 2];
#pragma unroll
    for (int off = 32; off > 0; off >>= 1) {
        p0 += __shfl_down(p0, off, 64);
        p1 += __shfl_down(p1, off, 64);
        p2 += __shfl_down(p2, off, 64);
    }
    __shared__ float red[4][3];
    __shared__ float par[8];
    __shared__ float accs[Cc];
    const int wave = threadIdx.x >> 6;
    if ((threadIdx.x & 63) == 0) { red[wave][0] = p0; red[wave][1] = p1; red[wave][2] = p2; }
    __syncthreads();
    if (threadIdx.x == 0) {
        float dx = red[0][0] + red[1][0] + red[2][0] + red[3][0] + boff[0];
        float dy = red[0][1] + red[1][1] + red[2][1] + red[3][1] + boff[1];
        float dz = red[0][2] + red[1][2] + red[2][2] + red[3][2] + boff[2];
        float x = qpos[q * 4 + 0], y = qpos[q * 4 + 1];
        float z = qpos[q * 4 + 2], r = qpos[q * 4 + 3];
        float sx = x + dx * exp2f(z - r);
        float sy = y + dy * exp2f(z + r);
        float sz = z + dz;
        float sg = sigma[0];
        float inv = 1.0f / (2.0f * sg * sg);
        float e[4]; float s = 0.f;
#pragma unroll
        for (int l = 0; l < 4; ++l) {
            float d = sz - (float)l;
            float w = __expf(-d * d * inv);
            e[l] = __expf(w);
            s += e[l];
        }
        float rs = 1.0f / s;
        par[0] = sx; par[1] = sy;
#pragma unroll
        for (int l = 0; l < 4; ++l) par[2 + l] = e[l] * rs;
    }
    __syncthreads();
    const float sx = par[0];
    const float sy = par[1];
    const float* const fs[4] = {f0, f1, f2, f3};
    const int HWs[4] = {100, 50, 25, 13};
    float acc = 0.f;
#pragma unroll
    for (int l = 0; l < 4; ++l) {
        const int W = HWs[l];
        float px = fminf(fmaxf(sx - 0.5f, 0.f), (float)(W - 1));
        float py = fminf(fmaxf(sy - 0.5f, 0.f), (float)(W - 1));
        float x0f = floorf(px), y0f = floorf(py);
        float wx = px - x0f, wy = py - y0f;
        int x0 = (int)x0f, y0 = (int)y0f;
        int x1 = min(x0 + 1, W - 1), y1 = min(y0 + 1, W - 1);
        const float* base = fs[l] + (size_t)((b * Cc + c) * W) * W;
        float v00 = base[y0 * W + x0];
        float v01 = base[y0 * W + x1];
        float v10 = base[y1 * W + x0];
        float v11 = base[y1 * W + x1];
        float top = v00 + wx * (v01 - v00);
        float bot = v10 + wx * (v11 - v10);
        acc += par[2 + l] * (top + wy * (bot - top));
    }
    accs[c] = acc;
    __syncthreads();
    const int c4 = (threadIdx.x & 63) * 4;
    f32x4 val = *(const f32x4*)&accs[c4];
    float* obase = out + (size_t)q * (Pc * Cc) + c4;
#pragma unroll
    for (int p = wave; p < Pc; p += 4) {
        __builtin_nontemporal_store(val, (f32x4*)(obase + p * Cc));
    }
}

extern "C" void kernel_launch(void* const* d_in, const int* in_sizes, int n_in,
                              void* d_out, int out_size, void* d_ws, size_t ws_size,
                              hipStream_t stream) {
    const float* f0    = (const float*)d_in[0];
    const float* f1    = (const float*)d_in[1];
    const float* f2    = (const float*)d_in[2];
    const float* f3    = (const float*)d_in[3];
    const float* qpos  = (const float*)d_in[4];
    const float* qcont = (const float*)d_in[5];
    const float* Woff  = (const float*)d_in[6];
    const float* boff  = (const float*)d_in[7];
    const float* sigma = (const float*)d_in[8];
    float* out = (float*)d_out;

    const size_t params_bytes = (size_t)Bc * Nc * 8 * sizeof(float);      // 76.8 KB
    const size_t outT_bytes   = (size_t)Bc * Cc * Nc * sizeof(float);     // 2.46 MB

    if (ws_size >= params_bytes + outT_bytes) {
        float* params = (float*)d_ws;
        float* outT   = (float*)((char*)d_ws + params_bytes);
        params_kernel<<<Bc * Nc / 4, 256, 0, stream>>>(qpos, qcont, Woff, boff, sigma, params);
        sample_kernel<<<Bc * Cc / 2, 256, 0, stream>>>(f0, f1, f2, f3, params, outT);
        broadcast_kernel<<<Bc * Nc, 256, 0, stream>>>(outT, out);
    } else {
        sampling3d_fallback<<<Bc * Nc, 256, 0, stream>>>(
            f0, f1, f2, f3, qpos, qcont, Woff, boff, sigma, out);
    }
}

// Round 12
// 188.149 us; speedup vs baseline: 1.0393x; 1.0393x over previous
//
#include <hip/hip_runtime.h>

// Problem constants (from reference setup_inputs)
constexpr int Bc = 8;
constexpr int Nc = 300;
constexpr int Cc = 256;
constexpr int Pc = 32;

typedef float f32x4 __attribute__((ext_vector_type(4)));

// Staged levels 1..3 only: 2500 + 625 + 169 floats
constexpr int L1_OFF = 0;
constexpr int L2_OFF = 2500;
constexpr int L3_OFF = 3125;
constexpr int STAGE_FLOATS = 3296;   // padded to 16B multiple

// ---- async global->LDS DMA ----
__device__ __forceinline__ void gl_lds16(const void* g, void* l) {
    __builtin_amdgcn_global_load_lds(
        (const __attribute__((address_space(1))) void*)g,
        (__attribute__((address_space(3))) void*)l, 16, 0, 0);
}
__device__ __forceinline__ void gl_lds4(const void* g, void* l) {
    __builtin_amdgcn_global_load_lds(
        (const __attribute__((address_space(1))) void*)g,
        (__attribute__((address_space(3))) void*)l, 4, 0, 0);
}

// ---------------------------------------------------------------------------
// Kernel 1: per-query params, one wave per query.
// params[q*8 + {0:sx, 1:sy, 2..5: zw[l], 6..7: unused}]
// ---------------------------------------------------------------------------
__global__ __launch_bounds__(256) void params_kernel(
    const float* __restrict__ qpos, const float* __restrict__ qcont,
    const float* __restrict__ Woff, const float* __restrict__ boff,
    const float* __restrict__ sigma, float* __restrict__ params)
{
    const int w = threadIdx.x >> 6;
    const int lane = threadIdx.x & 63;
    const int q = blockIdx.x * 4 + w;          // 600*4 = 2400 queries

    f32x4 qc = *(const f32x4*)&qcont[(size_t)q * Cc + lane * 4];
    float p0 = 0.f, p1 = 0.f, p2 = 0.f;
#pragma unroll
    for (int j = 0; j < 4; ++j) {
        const float* wr = &Woff[(lane * 4 + j) * 3];
        p0 += qc[j] * wr[0];
        p1 += qc[j] * wr[1];
        p2 += qc[j] * wr[2];
    }
#pragma unroll
    for (int off = 32; off > 0; off >>= 1) {
        p0 += __shfl_down(p0, off, 64);
        p1 += __shfl_down(p1, off, 64);
        p2 += __shfl_down(p2, off, 64);
    }
    if (lane == 0) {
        float dx = p0 + boff[0];
        float dy = p1 + boff[1];
        float dz = p2 + boff[2];
        float x = qpos[q * 4 + 0];
        float y = qpos[q * 4 + 1];
        float z = qpos[q * 4 + 2];
        float r = qpos[q * 4 + 3];
        float sx = x + dx * exp2f(z - r);
        float sy = y + dy * exp2f(z + r);
        float sz = z + dz;
        float sg = sigma[0];
        float inv = 1.0f / (2.0f * sg * sg);
        float e[4];
        float s = 0.f;
#pragma unroll
        for (int l = 0; l < 4; ++l) {
            float d = sz - (float)l;
            float wgt = __expf(-d * d * inv);  // gaussian weight in (0,1]
            e[l] = __expf(wgt);                // softmax numerator of that weight
            s += e[l];
        }
        float rs = 1.0f / s;
        params[q * 8 + 0] = sx;
        params[q * 8 + 1] = sy;
#pragma unroll
        for (int l = 0; l < 4; ++l) params[q * 8 + 2 + l] = e[l] * rs;
    }
}

// bilinear coords, border padding, align_corners=False
struct BilinW { int i00, i01, i10, i11; float wx, wy; };
__device__ __forceinline__ BilinW bilin(int W, float sx, float sy) {
    float px = fminf(fmaxf(sx - 0.5f, 0.f), (float)(W - 1));
    float py = fminf(fmaxf(sy - 0.5f, 0.f), (float)(W - 1));
    float x0f = floorf(px);
    float y0f = floorf(py);
    int x0 = (int)x0f;
    int y0 = (int)y0f;
    int x1 = min(x0 + 1, W - 1);
    int y1 = min(y0 + 1, W - 1);
    BilinW r;
    r.wx = px - x0f;
    r.wy = py - y0f;
    r.i00 = y0 * W + x0; r.i01 = y0 * W + x1;
    r.i10 = y1 * W + x0; r.i11 = y1 * W + x1;
    return r;
}
__device__ __forceinline__ float blend(float v00, float v01, float v10, float v11,
                                       float wx, float wy) {
    float top = v00 + wx * (v01 - v00);
    float bot = v10 + wx * (v11 - v10);
    return top + wy * (bot - top);
}

// ---------------------------------------------------------------------------
// Kernel 2 (R8 configuration — best measured): one block per (b,c) slice,
// grid 2048, __launch_bounds__(256,8) -> 8 blocks/CU, 32 waves/CU.
// Levels 1..3 staged to LDS via async DMA (13.2 KB); level 0 gathered
// directly from global (40 KB window -> L2-friendly).
// outT[(b*Cc + c)*Nc + n]  <- coalesced (thread index = n)
// ---------------------------------------------------------------------------
__global__ __launch_bounds__(256, 8) void sample_kernel(
    const float* __restrict__ f0, const float* __restrict__ f1,
    const float* __restrict__ f2, const float* __restrict__ f3,
    const float* __restrict__ params, float* __restrict__ outT)
{
    __shared__ __align__(16) float sl[STAGE_FLOATS];
    const int bc = blockIdx.x;           // b*Cc + c
    const int t = threadIdx.x;
    const int b = bc >> 8;
    const int wave = t >> 6;
    const int lane = t & 63;

    // ---- per-thread query params ----
    const int q0 = b * Nc + t;
    const bool has2 = (t < Nc - 256);    // t < 44
    f32x4 pa0 = *(const f32x4*)&params[(size_t)q0 * 8];      // {sx, sy, zw0, zw1}
    f32x4 pb0 = *(const f32x4*)&params[(size_t)q0 * 8 + 4];  // {zw2, zw3, -, -}
    f32x4 pa1 = {0, 0, 0, 0}, pb1 = {0, 0, 0, 0};
    if (has2) {
        pa1 = *(const f32x4*)&params[(size_t)(q0 + 256) * 8];
        pb1 = *(const f32x4*)&params[(size_t)(q0 + 256) * 8 + 4];
    }
    const float sx0 = pa0.x, sy0 = pa0.y;
    const float sx1 = pa1.x, sy1 = pa1.y;

    // ---- async-stage levels 1..3 (fire-and-forget; drained at barrier) ----
    {
        // level 1: 10000 B, 16B-aligned. 9 x 1024 B + 784 B tail (49 lanes).
        const char* g1 = (const char*)(f1 + (size_t)bc * 2500);
        char* l1 = (char*)&sl[L1_OFF];
        for (int i = wave; i < 9; i += 4)
            gl_lds16(g1 + i * 1024 + lane * 16, l1 + i * 1024);
        if (wave == 2 && lane < 49)
            gl_lds16(g1 + 9 * 1024 + lane * 16, l1 + 9 * 1024);
        // level 2: 2500 B, 4B-aligned -> width-4. 9 x 256 B + 196 B tail.
        const char* g2 = (const char*)(f2 + (size_t)bc * 625);
        char* l2 = (char*)&sl[L2_OFF];
        for (int i = wave; i < 9; i += 4)
            gl_lds4(g2 + i * 256 + lane * 4, l2 + i * 256);
        if (wave == 1 && lane < 49)
            gl_lds4(g2 + 9 * 256 + lane * 4, l2 + 9 * 256);
        // level 3: 676 B, 4B-aligned -> width-4. 2 x 256 B + 164 B tail.
        const char* g3 = (const char*)(f3 + (size_t)bc * 169);
        char* l3 = (char*)&sl[L3_OFF];
        for (int i = wave; i < 2; i += 4)
            gl_lds4(g3 + i * 256 + lane * 4, l3 + i * 256);
        if (wave == 3 && lane < 41)
            gl_lds4(g3 + 2 * 256 + lane * 4, l3 + 2 * 256);
    }

    // ---- level-0 direct gathers (issued before the barrier; overlap DMA) ----
    const float* base0 = f0 + (size_t)bc * 10000;
    const BilinW w00 = bilin(100, sx0, sy0);
    float a00 = base0[w00.i00];
    float a01 = base0[w00.i01];
    float a10 = base0[w00.i10];
    float a11 = base0[w00.i11];
    BilinW w01;
    float b00 = 0.f, b01 = 0.f, b10 = 0.f, b11 = 0.f;
    if (has2) {
        w01 = bilin(100, sx1, sy1);
        b00 = base0[w01.i00];
        b01 = base0[w01.i01];
        b10 = base0[w01.i10];
        b11 = base0[w01.i11];
    }

    __syncthreads();   // drains DMA (and gathers)

    // ---- combine: level 0 from registers, levels 1..3 from LDS ----
    {
        BilinW w1 = bilin(50, sx0, sy0);
        BilinW w2 = bilin(25, sx0, sy0);
        BilinW w3 = bilin(13, sx0, sy0);
        float acc = pa0.z * blend(a00, a01, a10, a11, w00.wx, w00.wy)
                  + pa0.w * blend(sl[L1_OFF + w1.i00], sl[L1_OFF + w1.i01],
                                  sl[L1_OFF + w1.i10], sl[L1_OFF + w1.i11], w1.wx, w1.wy)
                  + pb0.x * blend(sl[L2_OFF + w2.i00], sl[L2_OFF + w2.i01],
                                  sl[L2_OFF + w2.i10], sl[L2_OFF + w2.i11], w2.wx, w2.wy)
                  + pb0.y * blend(sl[L3_OFF + w3.i00], sl[L3_OFF + w3.i01],
                                  sl[L3_OFF + w3.i10], sl[L3_OFF + w3.i11], w3.wx, w3.wy);
        outT[(size_t)bc * Nc + t] = acc;
    }
    if (has2) {
        BilinW w1 = bilin(50, sx1, sy1);
        BilinW w2 = bilin(25, sx1, sy1);
        BilinW w3 = bilin(13, sx1, sy1);
        float acc = pa1.z * blend(b00, b01, b10, b11, w01.wx, w01.wy)
                  + pa1.w * blend(sl[L1_OFF + w1.i00], sl[L1_OFF + w1.i01],
                                  sl[L1_OFF + w1.i10], sl[L1_OFF + w1.i11], w1.wx, w1.wy)
                  + pb1.x * blend(sl[L2_OFF + w2.i00], sl[L2_OFF + w2.i01],
                                  sl[L2_OFF + w2.i10], sl[L2_OFF + w2.i11], w2.wx, w2.wy)
                  + pb1.y * blend(sl[L3_OFF + w3.i00], sl[L3_OFF + w3.i01],
                                  sl[L3_OFF + w3.i10], sl[L3_OFF + w3.i11], w3.wx, w3.wy);
        outT[(size_t)bc * Nc + t + 256] = acc;
    }
}

// ---------------------------------------------------------------------------
// Kernel 3: one block per query. Read 256 channel values (strided dwords,
// L2-absorbed: outT footprint 2.46 MB), broadcast over P with NT float4.
// ---------------------------------------------------------------------------
__global__ __launch_bounds__(256) void broadcast_kernel(
    const float* __restrict__ outT, float* __restrict__ out)
{
    __shared__ float sval[Cc];
    const int q = blockIdx.x;            // b*Nc + n
    const int b = q / Nc;
    const int n = q - b * Nc;
    const int c = threadIdx.x;
    sval[c] = outT[((size_t)(b * Cc + c)) * Nc + n];
    __syncthreads();

    const int wave = threadIdx.x >> 6;
    const int c4 = (threadIdx.x & 63) * 4;
    f32x4 val = *(const f32x4*)&sval[c4];
    float* obase = out + (size_t)q * (Pc * Cc) + c4;
#pragma unroll
    for (int p = wave; p < Pc; p += 4) {
        __builtin_nontemporal_store(val, (f32x4*)(obase + p * Cc));
    }
}

// ---------------------------------------------------------------------------
// Fallback: proven single-kernel path (if ws too small). Not expected to run.
// ---------------------------------------------------------------------------
__global__ __launch_bounds__(256) void sampling3d_fallback(
    const float* __restrict__ f0, const float* __restrict__ f1,
    const float* __restrict__ f2, const float* __restrict__ f3,
    const float* __restrict__ qpos, const float* __restrict__ qcont,
    const float* __restrict__ Woff, const float* __restrict__ boff,
    const float* __restrict__ sigma, float* __restrict__ out)
{
    const int q = blockIdx.x;
    const int b = q / Nc;
    const int c = threadIdx.x;
    float qc = qcont[q * Cc + c];
    float p0 = qc * Woff[c * 3 + 0];
    float p1 = qc * Woff[c * 3 + 1];
    float p2 = qc * Woff[c * 3 + 2];
#pragma unroll
    for (int off = 32; off > 0; off >>= 1) {
        p0 += __shfl_down(p0, off, 64);
        p1 += __shfl_down(p1, off, 64);
        p2 += __shfl_down(p2, off, 64);
    }
    __shared__ float red[4][3];
    __shared__ float par[8];
    __shared__ float accs[Cc];
    const int wave = threadIdx.x >> 6;
    if ((threadIdx.x & 63) == 0) { red[wave][0] = p0; red[wave][1] = p1; red[wave][2] = p2; }
    __syncthreads();
    if (threadIdx.x == 0) {
        float dx = red[0][0] + red[1][0] + red[2][0] + red[3][0] + boff[0];
        float dy = red[0][1] + red[1][1] + red[2][1] + red[3][1] + boff[1];
        float dz = red[0][2] + red[1][2] + red[2][2] + red[3][2] + boff[2];
        float x = qpos[q * 4 + 0], y = qpos[q * 4 + 1];
        float z = qpos[q * 4 + 2], r = qpos[q * 4 + 3];
        float sx = x + dx * exp2f(z - r);
        float sy = y + dy * exp2f(z + r);
        float sz = z + dz;
        float sg = sigma[0];
        float inv = 1.0f / (2.0f * sg * sg);
        float e[4]; float s = 0.f;
#pragma unroll
        for (int l = 0; l < 4; ++l) {
            float d = sz - (float)l;
            float w = __expf(-d * d * inv);
            e[l] = __expf(w);
            s += e[l];
        }
        float rs = 1.0f / s;
        par[0] = sx; par[1] = sy;
#pragma unroll
        for (int l = 0; l < 4; ++l) par[2 + l] = e[l] * rs;
    }
    __syncthreads();
    const float sx = par[0];
    const float sy = par[1];
    const float* const fs[4] = {f0, f1, f2, f3};
    const int HWs[4] = {100, 50, 25, 13};
    float acc = 0.f;
#pragma unroll
    for (int l = 0; l < 4; ++l) {
        const int W = HWs[l];
        float px = fminf(fmaxf(sx - 0.5f, 0.f), (float)(W - 1));
        float py = fminf(fmaxf(sy - 0.5f, 0.f), (float)(W - 1));
        float x0f = floorf(px), y0f = floorf(py);
        float wx = px - x0f, wy = py - y0f;
        int x0 = (int)x0f, y0 = (int)y0f;
        int x1 = min(x0 + 1, W - 1), y1 = min(y0 + 1, W - 1);
        const float* base = fs[l] + (size_t)((b * Cc + c) * W) * W;
        float v00 = base[y0 * W + x0];
        float v01 = base[y0 * W + x1];
        float v10 = base[y1 * W + x0];
        float v11 = base[y1 * W + x1];
        float top = v00 + wx * (v01 - v00);
        float bot = v10 + wx * (v11 - v10);
        acc += par[2 + l] * (top + wy * (bot - top));
    }
    accs[c] = acc;
    __syncthreads();
    const int c4 = (threadIdx.x & 63) * 4;
    f32x4 val = *(const f32x4*)&accs[c4];
    float* obase = out + (size_t)q * (Pc * Cc) + c4;
#pragma unroll
    for (int p = wave; p < Pc; p += 4) {
        __builtin_nontemporal_store(val, (f32x4*)(obase + p * Cc));
    }
}

extern "C" void kernel_launch(void* const* d_in, const int* in_sizes, int n_in,
                              void* d_out, int out_size, void* d_ws, size_t ws_size,
                              hipStream_t stream) {
    const float* f0    = (const float*)d_in[0];
    const float* f1    = (const float*)d_in[1];
    const float* f2    = (const float*)d_in[2];
    const float* f3    = (const float*)d_in[3];
    const float* qpos  = (const float*)d_in[4];
    const float* qcont = (const float*)d_in[5];
    const float* Woff  = (const float*)d_in[6];
    const float* boff  = (const float*)d_in[7];
    const float* sigma = (const float*)d_in[8];
    float* out = (float*)d_out;

    const size_t params_bytes = (size_t)Bc * Nc * 8 * sizeof(float);      // 76.8 KB
    const size_t outT_bytes   = (size_t)Bc * Cc * Nc * sizeof(float);     // 2.46 MB

    if (ws_size >= params_bytes + outT_bytes) {
        float* params = (float*)d_ws;
        float* outT   = (float*)((char*)d_ws + params_bytes);
        params_kernel<<<Bc * Nc / 4, 256, 0, stream>>>(qpos, qcont, Woff, boff, sigma, params);
        sample_kernel<<<Bc * Cc, 256, 0, stream>>>(f0, f1, f2, f3, params, outT);
        broadcast_kernel<<<Bc * Nc, 256, 0, stream>>>(outT, out);
    } else {
        sampling3d_fallback<<<Bc * Nc, 256, 0, stream>>>(
            f0, f1, f2, f3, qpos, qcont, Woff, boff, sigma, out);
    }
}